// Round 1
// 82.717 us; speedup vs baseline: 1.1195x; 1.1195x over previous
//
#include <hip/hip_runtime.h>

// SoftSymmetricAlignment: B=4, N=M=512, D=128, fp32.
// z[b,n,m] = sum_d |x[b,n,d]-y[b,m,d]|; alpha=softmax_n(-z), beta=softmax_m(-z)
// over the valid region only (masked -1e9 entries underflow to exactly 0);
// a = alpha+beta-alpha*beta; out[b] = -sum(a*z)/sum(a).
//
// R11: single delta vs R10 (92.6us): materialize z in the workspace instead of
// flash-style recompute. z is only 4 MB (L2-resident: 512 KB/XCD share), stored
// in a block-private [block][k][tid] float4 layout so every wave transaction is
// a contiguous 1 KB segment. k1 computes z once (unavoidable ~3.4us VALU/LDS
// balanced pass) + per-tile softmax partials + z store; k2 no longer stages
// x/y or recomputes z (was ~4-5us of LDS+VALU) -- it merges stats and reads
// its 16 KB z tile back (~1.5us). Exact same arithmetic on both sides -> still
// bit-exact (absmax 0.0).
// Kept from R10: TN=TM=64, 3 stream-ordered kernels, NO fences (R3/R4/R6:
// 20-40us on 8-XCD gfx950), no launch_bounds min-waves clause (R8/R9 spills),
// slotted accumulators + shfl-tree k3_out.

constexpr int B = 4, N = 512, M = 512, D = 128;
constexpr int TN = 64, TM = 64;
constexpr int LSTR = D + 4;           // +4 floats pad: rows shift 4 banks -> <=2-way conflicts
constexpr int NSLOT = 16;             // accumulator slots per quantity
#define SENT -3.0e38f                  // "minus infinity" that is exp-safe (no inf-inf NaN)

// lengths: jnp.int64 in the reference, but JAX w/o x64 gives int32. Lengths are
// >=64, so odd int32 slots are 0 iff the buffer is int64 little-endian.
__device__ __forceinline__ int load_len(const int* p, int b) {
  bool is64 = (p[1] == 0) && (p[3] == 0);
  return is64 ? p[2 * b] : p[b];
}

// Stage x/y 64x128 tiles into LDS; compute zr[4][4] for
// n = n0+ty+16i, m = m0+tx+16j (strided micro-tile; <=2-way LDS conflicts).
__device__ __forceinline__ void compute_tile(const float* __restrict__ x,
                                             const float* __restrict__ y,
                                             int b, int n0, int m0, int tid,
                                             float* xs, float* ys,
                                             float zr[4][4]) {
  const float4* xg = (const float4*)(x + (size_t)(b * N + n0) * D);
  const float4* yg = (const float4*)(y + (size_t)(b * M + m0) * D);
#pragma unroll
  for (int k = 0; k < 8; ++k) {
    int idx = tid + k * 256;     // float4 index within 64x128 tile (2048 total)
    int r = idx >> 5;            // 32 float4 per row
    int c = (idx & 31) << 2;
    *(float4*)&xs[r * LSTR + c] = xg[idx];
    *(float4*)&ys[r * LSTR + c] = yg[idx];
  }
  __syncthreads();

  const int tx = tid & 15;
  const int ty = tid >> 4;
#pragma unroll
  for (int i = 0; i < 4; ++i)
#pragma unroll
    for (int j = 0; j < 4; ++j) zr[i][j] = 0.f;

#pragma unroll 4
  for (int dd = 0; dd < D; dd += 4) {
    float4 xa[4], yb[4];
#pragma unroll
    for (int i = 0; i < 4; ++i) xa[i] = *(const float4*)&xs[(ty + 16 * i) * LSTR + dd];
#pragma unroll
    for (int j = 0; j < 4; ++j) yb[j] = *(const float4*)&ys[(tx + 16 * j) * LSTR + dd];
#pragma unroll
    for (int i = 0; i < 4; ++i)
#pragma unroll
      for (int j = 0; j < 4; ++j) {
        zr[i][j] += fabsf(xa[i].x - yb[j].x);
        zr[i][j] += fabsf(xa[i].y - yb[j].y);
        zr[i][j] += fabsf(xa[i].z - yb[j].z);
        zr[i][j] += fabsf(xa[i].w - yb[j].w);
      }
  }
}

// k1: compute z once; store the tile (block-private coalesced layout) + per-tile
// softmax partials.
//   rp[b][mt][n] = (max, sumexp) over this m-tile's valid m, for row n
//   cp[b][nt][m] = (max, sumexp) over this n-tile's valid n, for col m
//   zt[block][k][tid] = zr[k][0..3] as float4 (wave store = contiguous 1 KB)
__global__ __launch_bounds__(256) void k1_stats(const float* __restrict__ x,
                                                const float* __restrict__ y,
                                                const int* __restrict__ xlen,
                                                const int* __restrict__ ylen,
                                                float2* __restrict__ rp,
                                                float2* __restrict__ cp,
                                                float* __restrict__ acc,
                                                float* __restrict__ zt_all) {
  __shared__ float xs[TN * LSTR];
  __shared__ float ys[TM * LSTR];
  __shared__ float2 colp[4][TM];
  const int b  = blockIdx.z;
  const int n0 = blockIdx.y * TN;
  const int m0 = blockIdx.x * TM;
  const int tid = threadIdx.x;
  const int xl = load_len(xlen, b);
  const int yl = load_len(ylen, b);

  if (blockIdx.x == 0 && blockIdx.y == 0 && blockIdx.z == 0 && tid < 2 * B * NSLOT)
    acc[tid] = 0.f;   // visible to k2's atomics after kernel boundary

  float zr[4][4];
  compute_tile(x, y, b, n0, m0, tid, xs, ys, zr);

  // store z tile first: the 4 dwordx4 stores issue early and drain under the
  // shfl-heavy stats below.
  float* zt = zt_all + ((size_t)((b * 8 + (n0 >> 6)) * 8 + (m0 >> 6))) * (TN * TM);
#pragma unroll
  for (int i = 0; i < 4; ++i)
    *(float4*)&zt[(i * 256 + tid) * 4] =
        make_float4(zr[i][0], zr[i][1], zr[i][2], zr[i][3]);

  const int tx = tid & 15;
  const int ty = tid >> 4;
  const int wv = tid >> 6;

  // row partials: reduce over the 16 tx lanes (lane bits 0..3)
#pragma unroll
  for (int i = 0; i < 4; ++i) {
    float lm = SENT;
#pragma unroll
    for (int j = 0; j < 4; ++j)
      if (m0 + tx + 16 * j < yl) lm = fmaxf(lm, -zr[i][j]);
#pragma unroll
    for (int off = 1; off <= 8; off <<= 1) lm = fmaxf(lm, __shfl_xor(lm, off, 64));
    float ls = 0.f;
#pragma unroll
    for (int j = 0; j < 4; ++j)
      if (m0 + tx + 16 * j < yl) ls += __expf(-zr[i][j] - lm);
#pragma unroll
    for (int off = 1; off <= 8; off <<= 1) ls += __shfl_xor(ls, off, 64);
    if (tx == 0)
      rp[((b * 8 + (m0 >> 6)) * N) + n0 + ty + 16 * i] = make_float2(lm, ls);
  }

  // col partials: reduce ty within wave (lane bits 4..5), then 4 waves via LDS
#pragma unroll
  for (int j = 0; j < 4; ++j) {
    float cm = SENT;
#pragma unroll
    for (int i = 0; i < 4; ++i)
      if (n0 + ty + 16 * i < xl) cm = fmaxf(cm, -zr[i][j]);
    cm = fmaxf(cm, __shfl_xor(cm, 16, 64));
    cm = fmaxf(cm, __shfl_xor(cm, 32, 64));
    float cs = 0.f;
#pragma unroll
    for (int i = 0; i < 4; ++i)
      if (n0 + ty + 16 * i < xl) cs += __expf(-zr[i][j] - cm);
    cs += __shfl_xor(cs, 16, 64);
    cs += __shfl_xor(cs, 32, 64);
    if ((ty & 3) == 0) colp[wv][tx + 16 * j] = make_float2(cm, cs);
  }
  __syncthreads();
  if (tid < TM) {
    float2 p0 = colp[0][tid], p1 = colp[1][tid], p2 = colp[2][tid], p3 = colp[3][tid];
    float gm = fmaxf(fmaxf(p0.x, p1.x), fmaxf(p2.x, p3.x));
    float gs = p0.y * __expf(p0.x - gm) + p1.y * __expf(p1.x - gm) +
               p2.y * __expf(p2.x - gm) + p3.y * __expf(p3.x - gm);
    cp[((b * 8 + (n0 >> 6)) * M) + m0 + tid] = make_float2(gm, gs);
  }
}

// k2: merge this block's row/col stats, read the stored z tile back (no x/y
// staging, no z recompute), accumulate num/den into slotted accumulators.
__global__ __launch_bounds__(256) void k2_final(const int* __restrict__ xlen,
                                                const int* __restrict__ ylen,
                                                const float2* __restrict__ rp,
                                                const float2* __restrict__ cp,
                                                const float* __restrict__ zt_all,
                                                float* __restrict__ acc) {
  __shared__ float rm_s[TN], ri_s[TN], cm_s[TM], ci_s[TM];
  __shared__ float red[4][2];
  const int b  = blockIdx.z;
  const int n0 = blockIdx.y * TN;
  const int m0 = blockIdx.x * TM;
  const int tid = threadIdx.x;
  const int xl = load_len(xlen, b);
  const int yl = load_len(ylen, b);

  // issue the z reads first: independent of the stat merge, latency overlaps it
  const float* zt = zt_all + ((size_t)((b * 8 + (n0 >> 6)) * 8 + (m0 >> 6))) * (TN * TM);
  float4 zv[4];
#pragma unroll
  for (int i = 0; i < 4; ++i) zv[i] = *(const float4*)&zt[(i * 256 + tid) * 4];

  // merge the 8 per-tile partials for this block's rows (tid<64) / cols
  // (64<=tid<128); online-softmax rescale, masked partials contribute 0.
  if (tid < 128) {
    bool isrow = tid < 64;
    int p = isrow ? (n0 + tid) : (m0 + tid - 64);
    const float2* src = isrow ? rp : cp;
    float2 v[8];
    float gm = SENT;
#pragma unroll
    for (int t = 0; t < 8; ++t) {
      v[t] = src[(b * 8 + t) * 512 + p];
      gm = fmaxf(gm, v[t].x);
    }
    float gs = 0.f;
#pragma unroll
    for (int t = 0; t < 8; ++t) gs += v[t].y * __expf(v[t].x - gm);
    float inv = 1.0f / gs;            // inf only for fully-masked rows/cols (unused)
    if (isrow) { rm_s[tid] = gm; ri_s[tid] = inv; }
    else       { cm_s[tid - 64] = gm; ci_s[tid - 64] = inv; }
  }
  __syncthreads();

  const int tx = tid & 15;
  const int ty = tid >> 4;
  float num = 0.f, den = 0.f;
#pragma unroll
  for (int i = 0; i < 4; ++i) {
    int nl = ty + 16 * i;
    if (n0 + nl >= xl) continue;
    float rm = rm_s[nl], ri = ri_s[nl];
    float zrow[4] = {zv[i].x, zv[i].y, zv[i].z, zv[i].w};
#pragma unroll
    for (int j = 0; j < 4; ++j) {
      int ml = tx + 16 * j;
      if (m0 + ml >= yl) continue;
      float zval = zrow[j];
      float w = -zval;
      float alpha = __expf(w - cm_s[ml]) * ci_s[ml];
      float beta  = __expf(w - rm) * ri;
      float a = alpha + beta - alpha * beta;
      num += a * zval;
      den += a;
    }
  }
#pragma unroll
  for (int off = 32; off > 0; off >>= 1) {
    num += __shfl_xor(num, off, 64);
    den += __shfl_xor(den, off, 64);
  }
  if ((tid & 63) == 0) { red[tid >> 6][0] = num; red[tid >> 6][1] = den; }
  __syncthreads();
  if (tid == 0) {
    int slot = (blockIdx.x + blockIdx.y) & (NSLOT - 1);
    atomicAdd(&acc[b * NSLOT + slot],
              red[0][0] + red[1][0] + red[2][0] + red[3][0]);
    atomicAdd(&acc[(B + b) * NSLOT + slot],
              red[0][1] + red[1][1] + red[2][1] + red[3][1]);
  }
}

// One wave. acc layout: quantity q (0..3 = num[b], 4..7 = den[b]) x 16 slots.
// Lane l holds acc[l] (q = l>>4) and acc[64+l] (q = 4 + (l>>4)); shfl-xor over
// the 16-lane group reduces both; group-leader lane b*16 writes out[b].
__global__ void k3_out(const float* __restrict__ acc, float* __restrict__ out) {
  int l = threadIdx.x;
  float a = acc[l];
  float d = acc[64 + l];
#pragma unroll
  for (int off = 1; off <= 8; off <<= 1) {
    a += __shfl_xor(a, off, 64);
    d += __shfl_xor(d, off, 64);
  }
  if ((l & 15) == 0) out[l >> 4] = -a / d;
}

extern "C" void kernel_launch(void* const* d_in, const int* in_sizes, int n_in,
                              void* d_out, int out_size, void* d_ws, size_t ws_size,
                              hipStream_t stream) {
  const float* x    = (const float*)d_in[0];
  const float* y    = (const float*)d_in[1];
  const int*   xlen = (const int*)d_in[2];
  const int*   ylen = (const int*)d_in[3];
  float* out = (float*)d_out;

  float* ws = (float*)d_ws;
  float2* rp  = (float2*)ws;              size_t off = (size_t)B * 8 * N * 2;  // 128 KB
  float2* cp  = (float2*)(ws + off);      off += (size_t)B * 8 * M * 2;        // 128 KB
  float*  acc = ws + off;                 off += 2 * B * NSLOT;                // 512 B
  float*  zt  = ws + off;                 off += (size_t)B * 8 * 8 * TN * TM;  // 4 MB

  k1_stats<<<dim3(M / TM, N / TN, B), 256, 0, stream>>>(x, y, xlen, ylen, rp, cp, acc, zt);
  k2_final<<<dim3(M / TM, N / TN, B), 256, 0, stream>>>(xlen, ylen, rp, cp, zt, acc);
  k3_out<<<1, 64, 0, stream>>>(acc, out);
}

// Round 2
// 82.239 us; speedup vs baseline: 1.1260x; 1.0058x over previous
//
#include <hip/hip_runtime.h>

// SoftSymmetricAlignment: B=4, N=M=512, D=128, fp32.
// z[b,n,m] = sum_d |x[b,n,d]-y[b,m,d]|; alpha=softmax_n(-z), beta=softmax_m(-z)
// over the valid region only; a = alpha+beta-alpha*beta;
// out[b] = -sum(a*z)/sum(a).
//
// R12: single delta vs R11 (82.7us): exploit the length masks. Lengths are in
// [64,512] (E~288), so only ~32% of the z grid is valid. R11's 64x64 tiles map
// 1:1 onto the 256 CUs, so skipping masked tiles would just idle CUs. Switch
// to 32x32 tiles (grid 16x16x4 = 1024 blocks = 4/CU) with whole-block early
// exit: valid ~440 quarter-size blocks backfill across CUs -> z-pass critical
// path ~halves. k2's stat merge loops only over the ceil(len/32) partial tiles
// that valid k1 blocks actually wrote (no placeholder writes, no poison reads).
// Kept from R11: stored-z (no recompute), 3 stream-ordered kernels, NO fences
// (R3/R4/R6: 20-40us on 8-XCD gfx950), slotted accumulators + shfl-tree k3.

constexpr int B = 4, N = 512, M = 512, D = 128;
constexpr int TN = 32, TM = 32;       // fine tiles for masked-work skipping
constexpr int NT = 16;                // tiles per axis (512/32)
constexpr int LSTR = D + 4;           // +4 floats pad: rows shift 4 banks -> <=2-way conflicts
constexpr int NSLOT = 16;             // accumulator slots per quantity
#define SENT -3.0e38f                  // "minus infinity" that is exp-safe (no inf-inf NaN)

// lengths: jnp.int64 in the reference, but JAX w/o x64 gives int32. Lengths are
// >=64, so odd int32 slots are 0 iff the buffer is int64 little-endian.
__device__ __forceinline__ int load_len(const int* p, int b) {
  bool is64 = (p[1] == 0) && (p[3] == 0);
  return is64 ? p[2 * b] : p[b];
}

// k1: compute z for one 32x32 tile (2x2 micro-tile per thread), store it +
// per-tile softmax partials.
//   rp[b][mt][n] = (max, sumexp) over this m-tile's valid m, for row n
//   cp[b][nt][m] = (max, sumexp) over this n-tile's valid n, for col m
//   zt[tile][i][tid] = {zr[i][0], zr[i][1]} float2 (coalesced 8B/lane)
__global__ __launch_bounds__(256) void k1_stats(const float* __restrict__ x,
                                                const float* __restrict__ y,
                                                const int* __restrict__ xlen,
                                                const int* __restrict__ ylen,
                                                float2* __restrict__ rp,
                                                float2* __restrict__ cp,
                                                float* __restrict__ acc,
                                                float* __restrict__ zt_all) {
  __shared__ float xs[TN * LSTR];
  __shared__ float ys[TM * LSTR];
  __shared__ float2 colp[4][TM];
  const int b  = blockIdx.z;
  const int n0 = blockIdx.y * TN;
  const int m0 = blockIdx.x * TM;
  const int tid = threadIdx.x;
  const int xl = load_len(xlen, b);
  const int yl = load_len(ylen, b);

  if (blockIdx.x == 0 && blockIdx.y == 0 && blockIdx.z == 0 && tid < 2 * B * NSLOT)
    acc[tid] = 0.f;   // block (0,0,0) is always valid (lengths >= 64)

  if (n0 >= xl || m0 >= yl) return;   // fully-masked tile: contributes nothing

  // stage x/y 32x128 tiles (16 KB each); 4 float4 per thread per tile
  {
    const float4* xg = (const float4*)(x + (size_t)(b * N + n0) * D);
    const float4* yg = (const float4*)(y + (size_t)(b * M + m0) * D);
#pragma unroll
    for (int k = 0; k < 4; ++k) {
      int idx = tid + k * 256;   // float4 index within 32x128 tile (1024 total)
      int r = idx >> 5;          // 32 float4 per row
      int c = (idx & 31) << 2;
      *(float4*)&xs[r * LSTR + c] = xg[idx];
      *(float4*)&ys[r * LSTR + c] = yg[idx];
    }
  }
  __syncthreads();

  const int tx = tid & 15;       // m = m0 + tx + 16j, j<2
  const int ty = tid >> 4;       // n = n0 + ty + 16i, i<2
  float zr[2][2] = {{0.f, 0.f}, {0.f, 0.f}};

#pragma unroll 4
  for (int dd = 0; dd < D; dd += 4) {
    float4 xa[2], yb[2];
#pragma unroll
    for (int i = 0; i < 2; ++i) xa[i] = *(const float4*)&xs[(ty + 16 * i) * LSTR + dd];
#pragma unroll
    for (int j = 0; j < 2; ++j) yb[j] = *(const float4*)&ys[(tx + 16 * j) * LSTR + dd];
#pragma unroll
    for (int i = 0; i < 2; ++i)
#pragma unroll
      for (int j = 0; j < 2; ++j) {
        zr[i][j] += fabsf(xa[i].x - yb[j].x);
        zr[i][j] += fabsf(xa[i].y - yb[j].y);
        zr[i][j] += fabsf(xa[i].z - yb[j].z);
        zr[i][j] += fabsf(xa[i].w - yb[j].w);
      }
  }

  // store z tile first: stores issue early and drain under the shfl-heavy stats
  float* zt = zt_all + ((size_t)((b * NT + (n0 >> 5)) * NT + (m0 >> 5))) * (TN * TM);
#pragma unroll
  for (int i = 0; i < 2; ++i)
    *(float2*)&zt[(i * 256 + tid) * 2] = make_float2(zr[i][0], zr[i][1]);

  const int wv = tid >> 6;

  // row partials: reduce over the 16 tx lanes (lane bits 0..3)
#pragma unroll
  for (int i = 0; i < 2; ++i) {
    float lm = SENT;
#pragma unroll
    for (int j = 0; j < 2; ++j)
      if (m0 + tx + 16 * j < yl) lm = fmaxf(lm, -zr[i][j]);
#pragma unroll
    for (int off = 1; off <= 8; off <<= 1) lm = fmaxf(lm, __shfl_xor(lm, off, 64));
    float ls = 0.f;
#pragma unroll
    for (int j = 0; j < 2; ++j)
      if (m0 + tx + 16 * j < yl) ls += __expf(-zr[i][j] - lm);
#pragma unroll
    for (int off = 1; off <= 8; off <<= 1) ls += __shfl_xor(ls, off, 64);
    if (tx == 0)
      rp[((b * NT + (m0 >> 5)) * N) + n0 + ty + 16 * i] = make_float2(lm, ls);
  }

  // col partials: reduce ty within wave (lane bits 4..5), then 4 waves via LDS
#pragma unroll
  for (int j = 0; j < 2; ++j) {
    float cm = SENT;
#pragma unroll
    for (int i = 0; i < 2; ++i)
      if (n0 + ty + 16 * i < xl) cm = fmaxf(cm, -zr[i][j]);
    cm = fmaxf(cm, __shfl_xor(cm, 16, 64));
    cm = fmaxf(cm, __shfl_xor(cm, 32, 64));
    float cs = 0.f;
#pragma unroll
    for (int i = 0; i < 2; ++i)
      if (n0 + ty + 16 * i < xl) cs += __expf(-zr[i][j] - cm);
    cs += __shfl_xor(cs, 16, 64);
    cs += __shfl_xor(cs, 32, 64);
    if ((ty & 3) == 0) colp[wv][tx + 16 * j] = make_float2(cm, cs);
  }
  __syncthreads();
  if (tid < TM) {
    float2 p0 = colp[0][tid], p1 = colp[1][tid], p2 = colp[2][tid], p3 = colp[3][tid];
    float gm = fmaxf(fmaxf(p0.x, p1.x), fmaxf(p2.x, p3.x));
    float gs = p0.y * __expf(p0.x - gm) + p1.y * __expf(p1.x - gm) +
               p2.y * __expf(p2.x - gm) + p3.y * __expf(p3.x - gm);
    cp[((b * NT + (n0 >> 5)) * M) + m0 + tid] = make_float2(gm, gs);
  }
}

// k2: merge this block's row/col stats (online softmax over only the
// ceil(len/32) partial tiles that exist), read the stored z tile back,
// accumulate num/den into slotted accumulators.
__global__ __launch_bounds__(256) void k2_final(const int* __restrict__ xlen,
                                                const int* __restrict__ ylen,
                                                const float2* __restrict__ rp,
                                                const float2* __restrict__ cp,
                                                const float* __restrict__ zt_all,
                                                float* __restrict__ acc) {
  __shared__ float rm_s[TN], ri_s[TN], cm_s[TM], ci_s[TM];
  __shared__ float red[4][2];
  const int b  = blockIdx.z;
  const int n0 = blockIdx.y * TN;
  const int m0 = blockIdx.x * TM;
  const int tid = threadIdx.x;
  const int xl = load_len(xlen, b);
  const int yl = load_len(ylen, b);

  if (n0 >= xl || m0 >= yl) return;   // fully-masked tile

  const int ntm = (yl + 31) >> 5;     // #m-tiles written (for row stats)
  const int ntn = (xl + 31) >> 5;     // #n-tiles written (for col stats)

  // issue the z reads first: independent of the stat merge, latency overlaps it
  const float* zt = zt_all + ((size_t)((b * NT + (n0 >> 5)) * NT + (m0 >> 5))) * (TN * TM);
  float2 zv[2];
#pragma unroll
  for (int i = 0; i < 2; ++i) zv[i] = *(const float2*)&zt[(i * 256 + tid) * 2];

  // merge partials: rows (tid<32) / cols (32<=tid<64), online-softmax; only
  // tiles t < ntm/ntn were written by valid k1 blocks (others never touched).
  if (tid < 64) {
    bool isrow = tid < 32;
    int p = isrow ? (n0 + tid) : (m0 + tid - 32);
    int cnt = isrow ? ntm : ntn;
    const float2* src = isrow ? rp : cp;
    float gm = SENT, gs = 0.f;
    for (int t = 0; t < cnt; ++t) {
      float2 v = src[(b * NT + t) * 512 + p];
      float nm = fmaxf(gm, v.x);
      gs = gs * __expf(gm - nm) + v.y * __expf(v.x - nm);
      gm = nm;
    }
    float inv = 1.0f / gs;            // inf only for fully-masked rows/cols (unused)
    if (isrow) { rm_s[tid] = gm; ri_s[tid] = inv; }
    else       { cm_s[tid - 32] = gm; ci_s[tid - 32] = inv; }
  }
  __syncthreads();

  const int tx = tid & 15;
  const int ty = tid >> 4;
  float num = 0.f, den = 0.f;
#pragma unroll
  for (int i = 0; i < 2; ++i) {
    int nl = ty + 16 * i;
    if (n0 + nl >= xl) continue;
    float rm = rm_s[nl], ri = ri_s[nl];
    float zrow[2] = {zv[i].x, zv[i].y};
#pragma unroll
    for (int j = 0; j < 2; ++j) {
      int ml = tx + 16 * j;
      if (m0 + ml >= yl) continue;
      float zval = zrow[j];
      float w = -zval;
      float alpha = __expf(w - cm_s[ml]) * ci_s[ml];
      float beta  = __expf(w - rm) * ri;
      float a = alpha + beta - alpha * beta;
      num += a * zval;
      den += a;
    }
  }
#pragma unroll
  for (int off = 32; off > 0; off >>= 1) {
    num += __shfl_xor(num, off, 64);
    den += __shfl_xor(den, off, 64);
  }
  if ((tid & 63) == 0) { red[tid >> 6][0] = num; red[tid >> 6][1] = den; }
  __syncthreads();
  if (tid == 0) {
    int slot = (blockIdx.x + blockIdx.y) & (NSLOT - 1);
    atomicAdd(&acc[b * NSLOT + slot],
              red[0][0] + red[1][0] + red[2][0] + red[3][0]);
    atomicAdd(&acc[(B + b) * NSLOT + slot],
              red[0][1] + red[1][1] + red[2][1] + red[3][1]);
  }
}

// One wave. acc layout: quantity q (0..3 = num[b], 4..7 = den[b]) x 16 slots.
// Lane l holds acc[l] (q = l>>4) and acc[64+l] (q = 4 + (l>>4)); shfl-xor over
// the 16-lane group reduces both; group-leader lane b*16 writes out[b].
__global__ void k3_out(const float* __restrict__ acc, float* __restrict__ out) {
  int l = threadIdx.x;
  float a = acc[l];
  float d = acc[64 + l];
#pragma unroll
  for (int off = 1; off <= 8; off <<= 1) {
    a += __shfl_xor(a, off, 64);
    d += __shfl_xor(d, off, 64);
  }
  if ((l & 15) == 0) out[l >> 4] = -a / d;
}

extern "C" void kernel_launch(void* const* d_in, const int* in_sizes, int n_in,
                              void* d_out, int out_size, void* d_ws, size_t ws_size,
                              hipStream_t stream) {
  const float* x    = (const float*)d_in[0];
  const float* y    = (const float*)d_in[1];
  const int*   xlen = (const int*)d_in[2];
  const int*   ylen = (const int*)d_in[3];
  float* out = (float*)d_out;

  float* ws = (float*)d_ws;
  float2* rp  = (float2*)ws;              size_t off = (size_t)B * NT * N * 2;  // 256 KB
  float2* cp  = (float2*)(ws + off);      off += (size_t)B * NT * M * 2;        // 256 KB
  float*  acc = ws + off;                 off += 2 * B * NSLOT;                 // 512 B
  float*  zt  = ws + off;                 off += (size_t)B * NT * NT * TN * TM; // 4 MB

  k1_stats<<<dim3(M / TM, N / TN, B), 256, 0, stream>>>(x, y, xlen, ylen, rp, cp, acc, zt);
  k2_final<<<dim3(M / TM, N / TN, B), 256, 0, stream>>>(xlen, ylen, rp, cp, zt, acc);
  k3_out<<<1, 64, 0, stream>>>(acc, out);
}